// Round 2
// baseline (472.268 us; speedup 1.0000x reference)
//
#include <hip/hip_runtime.h>
#include <math.h>

// Problem dims
#define Bq 16
#define Tq 2048
#define Dq 1024
#define Vq 640
#define NTOK (Bq*Tq)          // 32768
#define KT 32                 // K-tiles of 32 fp32 k each

// ws layout (bytes)
#define LOGITS_OFF 0UL
#define HIST_OFF   83886080UL            // NTOK*Vq*4
#define IDX_OFF    89128960UL            // + Tq*Vq*4
#define VAL_OFF    89260032UL            // + NTOK*4
#define CBC_OFF    89391104UL            // + NTOK*4   (16B aligned)
#define ACC_OFF    92012544UL            // + 32*5*16384

typedef _Float16 half4 __attribute__((ext_vector_type(4)));
typedef _Float16 half8 __attribute__((ext_vector_type(8)));
typedef float    f32x16 __attribute__((ext_vector_type(16)));

// ---------------- K0: convert codebook fp32 -> tiled swizzled f16 hi/lo ----------------
// Layout: per (k-tile t in [0,32), panel p in [0,5)) a 16KB block [r(128)][128B],
// row bytes: [hi(o0) lo(o0) hi(o1) lo(o1) hi(o2) lo(o2) hi(o3) lo(o3)] (o = 8-k octet),
// each row's bytes XOR-swizzled with ((r&7)<<4).
__global__ __launch_bounds__(256) void k_convB(const float* __restrict__ cb,
                                               _Float16* __restrict__ cbc)
{
    const int t = blockIdx.x / 5, p = blockIdx.x % 5;
    const int tid = threadIdx.x;
    const int sr  = tid >> 3;          // row 0..31 (+32*s)
    const int skk = (tid & 7) * 4;     // k offset in tile
    const int so  = (tid & 7) >> 1;    // octet 0..3
    const int sh  = tid & 1;           // half-octet
    char* dst = (char*)cbc + (long)(t * 5 + p) * 16384;
    const int boff = sr * 128 + ((so * 32 + sh * 8) ^ ((sr & 7) << 4));
    const float* src = cb + (long)(p * 128 + sr) * Dq + t * 32 + skk;
#pragma unroll
    for (int s = 0; s < 4; ++s) {
        float4 f = *(const float4*)(src + (long)s * 32 * Dq);
        float ff[4] = {f.x, f.y, f.z, f.w};
        half4 hi, lo;
#pragma unroll
        for (int j = 0; j < 4; ++j) {
            _Float16 h = (_Float16)ff[j];
            hi[j] = h;
            lo[j] = (_Float16)(ff[j] - (float)h);
        }
        *(half4*)(dst + boff + s * 4096) = hi;
        *(half4*)(dst + (boff ^ 16) + s * 4096) = lo;
    }
}

// ---------------- K1: logits = z @ codebook^T via split-f16 MFMA ----------------
// 128x128 tile, 4 waves (2x2), each wave 64x64 = 2x2 frags of 32x32.
// Per physical k-octet: MFMA pass1 (B in place) = hi*hi + lo*lo,
// pass2 (B addr^16) = hi*lo + lo*hi  ->  exact fp32 product up to 2^-22 splits.
__global__ __launch_bounds__(256) void k_gemm(const float* __restrict__ z,
                                              const _Float16* __restrict__ cbc,
                                              float* __restrict__ logits)
{
    __shared__ __align__(16) char smem[32768];
    char* AsB = smem;            // A tile [128][128B] swizzled
    char* BsB = smem + 16384;    // B tile [128][128B] swizzled

    const int tid  = threadIdx.x;
    const int lane = tid & 63;
    const int w    = tid >> 6;
    const int wm   = w >> 1, wn = w & 1;

    // XCD-aware swizzle (1280 = 8*160, bijective)
    int bid = blockIdx.x;
    bid = (bid & 7) * 160 + (bid >> 3);
    const int  colblk = bid % 5;
    const long row0   = (long)(bid / 5) * 128;
    const int  col0   = colblk * 128;

    // A staging constants (fused fp32->hi/lo convert, reg path)
    const int sr  = tid >> 3;
    const int skk = (tid & 7) * 4;
    const int so  = (tid & 7) >> 1;
    const int sh  = tid & 1;
    const int a_st = sr * 128 + ((so * 32 + sh * 8) ^ ((sr & 7) << 4));
    const float* zrow = z + (row0 + sr) * (long)Dq + skk;

    const char* cbb = (const char*)cbc;

    // fragment read constants
    const int l31 = lane & 31, lh = lane >> 5;
    const int swz = (l31 & 7) << 4;
    const int a_base0 = (wm * 64 + l31) * 128;
    const int a_base1 = a_base0 + 32 * 128;
    const int b_base0 = (wn * 64 + l31) * 128;
    const int b_base1 = b_base0 + 32 * 128;

    f32x16 acc[2][2] = {};

    for (int t = 0; t < KT; ++t) {
        // ---- stage B (pre-converted, pre-swizzled; linear 16KB copy) ----
        const char* bsrc = cbb + (long)(t * 5 + colblk) * 16384;
#pragma unroll
        for (int s = 0; s < 4; ++s) {
            half8 bv = *(const half8*)(bsrc + s * 4096 + tid * 16);
            *(half8*)(BsB + s * 4096 + tid * 16) = bv;
        }
        // ---- stage A: load fp32, split to f16 hi/lo, swizzled ds_write ----
        float4 v[4];
        const float* zt = zrow + t * 32;
#pragma unroll
        for (int s = 0; s < 4; ++s) v[s] = *(const float4*)(zt + (long)s * 32 * Dq);
#pragma unroll
        for (int s = 0; s < 4; ++s) {
            float ff[4] = {v[s].x, v[s].y, v[s].z, v[s].w};
            half4 hi, lo;
#pragma unroll
            for (int j = 0; j < 4; ++j) {
                _Float16 h = (_Float16)ff[j];
                hi[j] = h;
                lo[j] = (_Float16)(ff[j] - (float)h);
            }
            *(half4*)(AsB + a_st + s * 4096) = hi;
            *(half4*)(AsB + (a_st ^ 16) + s * 4096) = lo;
        }
        __syncthreads();

        // ---- compute: 4 octets x 2 passes x 2x2 frags = 32 MFMA ----
#pragma unroll
        for (int o = 0; o < 4; ++o) {
            const int ko = (o * 32 + lh * 16) ^ swz;
            half8 a0 = *(const half8*)(AsB + a_base0 + ko);
            half8 a1 = *(const half8*)(AsB + a_base1 + ko);
#pragma unroll
            for (int fn = 0; fn < 2; ++fn) {
                const int bb = (fn ? b_base1 : b_base0);
                half8 b  = *(const half8*)(BsB + bb + ko);
                half8 bx = *(const half8*)(BsB + bb + (ko ^ 16));
                acc[0][fn] = __builtin_amdgcn_mfma_f32_32x32x16_f16(a0, b,  acc[0][fn], 0, 0, 0);
                acc[1][fn] = __builtin_amdgcn_mfma_f32_32x32x16_f16(a1, b,  acc[1][fn], 0, 0, 0);
                acc[0][fn] = __builtin_amdgcn_mfma_f32_32x32x16_f16(a0, bx, acc[0][fn], 0, 0, 0);
                acc[1][fn] = __builtin_amdgcn_mfma_f32_32x32x16_f16(a1, bx, acc[1][fn], 0, 0, 0);
            }
        }
        __syncthreads();
    }

    // ---- epilogue: C/D layout col=lane&31, row=(reg&3)+8*(reg>>2)+4*(lane>>5) ----
#pragma unroll
    for (int fm = 0; fm < 2; ++fm)
#pragma unroll
        for (int fn = 0; fn < 2; ++fn)
#pragma unroll
            for (int r = 0; r < 16; ++r) {
                const int rr = (r & 3) + 8 * (r >> 2) + 4 * lh;
                const long row = row0 + wm * 64 + fm * 32 + rr;
                const int  col = col0 + wn * 64 + fn * 32 + l31;
                logits[row * Vq + col] = acc[fm][fn][r];
            }
}

// ------------- K2: fused gumbel-add + max/argmax/denom + histogram -------------
__global__ __launch_bounds__(256) void k_softmax(const float* __restrict__ logits,
                                                 const float* __restrict__ gumbel,
                                                 int* __restrict__ oidx,
                                                 float* __restrict__ oval,
                                                 float* __restrict__ hist)
{
    const int  lane = threadIdx.x & 63;
    const long tok  = (long)blockIdx.x * 4 + (threadIdx.x >> 6);
    const float* lr = logits + tok * Vq;
    const float* gr = gumbel + tok * Vq;

    float x[10];
    float m = -3.4e38f; int mi = 0x7fffffff;
#pragma unroll
    for (int j = 0; j < 10; ++j) {
        const int c = lane + 64 * j;
        x[j] = lr[c] + gr[c];          // TAU == 1
        if (x[j] > m) { m = x[j]; mi = c; }
    }
#pragma unroll
    for (int off = 32; off; off >>= 1) {
        float om  = __shfl_xor(m, off);
        int   omi = __shfl_xor(mi, off);
        if (om > m || (om == m && omi < mi)) { m = om; mi = omi; }
    }
    float s = 0.f;
#pragma unroll
    for (int j = 0; j < 10; ++j) s += expf(x[j] - m);
#pragma unroll
    for (int off = 32; off; off >>= 1) s += __shfl_xor(s, off);

    if (lane == 0) {
        const float p   = 1.0f / s;
        const float val = (1.0f - p) + p;    // reference's (y_hard - sg(y_soft) + y_soft)
        oidx[tok] = mi;
        oval[tok] = val;
        const int t = (int)(tok % Tq);
        atomicAdd(&hist[(long)t * Vq + mi], val);
    }
}

// ------------- K3: quantized[tok] = val * W_p[idx[tok]] -------------
__global__ __launch_bounds__(256) void k_gather(const float* __restrict__ Wp,
                                                const int* __restrict__ idx,
                                                const float* __restrict__ val,
                                                float* __restrict__ out)
{
    const long tok = blockIdx.x;
    const int  v   = idx[tok];
    const float s  = val[tok];
    const float4* src = (const float4*)(Wp + (long)v * Dq);
    float4*       dst = (float4*)(out + tok * Dq);
    float4 w = src[threadIdx.x];
    dst[threadIdx.x] = make_float4(w.x * s, w.y * s, w.z * s, w.w * s);
}

// ------------- K4: entropy of avg_probs -------------
__global__ __launch_bounds__(256) void k_entropy(const float* __restrict__ hist,
                                                 double* __restrict__ accum)
{
    double local = 0.0;
    const long n = (long)Tq * Vq;
    for (long i = (long)blockIdx.x * 256 + threadIdx.x; i < n; i += (long)gridDim.x * 256) {
        const float avg = hist[i] * 0.0625f;               // /16
        local += (double)(-avg * logf(avg + 1e-10f));      // avg==0 -> exactly 0
    }
#pragma unroll
    for (int off = 32; off; off >>= 1) local += __shfl_xor(local, off);
    __shared__ double red[4];
    const int lane = threadIdx.x & 63, w = threadIdx.x >> 6;
    if (lane == 0) red[w] = local;
    __syncthreads();
    if (threadIdx.x == 0) atomicAdd(accum, red[0] + red[1] + red[2] + red[3]);
}

__global__ void k_final(const double* __restrict__ accum, float* __restrict__ out)
{
    out[0] = (float)(accum[0] / (double)Tq);
}

extern "C" void kernel_launch(void* const* d_in, const int* in_sizes, int n_in,
                              void* d_out, int out_size, void* d_ws, size_t ws_size,
                              hipStream_t stream)
{
    const float* z   = (const float*)d_in[0];
    const float* cb  = (const float*)d_in[1];
    const float* wp  = (const float*)d_in[2];
    const float* gum = (const float*)d_in[3];
    float* out = (float*)d_out;

    char* ws = (char*)d_ws;
    float*     logits = (float*)(ws + LOGITS_OFF);
    float*     hist   = (float*)(ws + HIST_OFF);
    int*       idx    = (int*)  (ws + IDX_OFF);
    float*     val    = (float*)(ws + VAL_OFF);
    _Float16*  cbc    = (_Float16*)(ws + CBC_OFF);
    double*    accum  = (double*)(ws + ACC_OFF);

    hipMemsetAsync(hist, 0, (size_t)Tq * Vq * 4, stream);
    hipMemsetAsync(accum, 0, 8, stream);

    k_convB  <<<160, 256, 0, stream>>>(cb, cbc);
    k_gemm   <<<1280, 256, 0, stream>>>(z, cbc, logits);
    k_softmax<<<NTOK / 4, 256, 0, stream>>>(logits, gum, idx, val, hist);
    k_gather <<<NTOK, 256, 0, stream>>>(wp, idx, val, out);
    k_entropy<<<128, 256, 0, stream>>>(hist, accum);
    k_final  <<<1, 1, 0, stream>>>(accum, out + (long)NTOK * Dq);
}